// Round 9
// baseline (227.061 us; speedup 1.0000x reference)
//
#include <hip/hip_runtime.h>

#define NN 1536
#define NE 49152
#define FIN 27
#define HD 64
#define LDIM 32
#define PP 1178880        // NN*(NN-1)/2
#define CAP 128           // padded-CSR row capacity (in-deg ~Poisson(32); passed at 128)
#define NTILE 1200        // 16x64 upper-tri tiles: sum_{cg=0..23} 4*(cg+1)

#define EL_OFF  (NN*FIN)            // 41472
#define MU_OFF  (EL_OFF + PP)       // 1220352
#define LV_OFF  (MU_OFF + NN*LDIM)  // 1269504
#define GMU_OFF (LV_OFF + NN*LDIM)  // 1318656
#define GLV_OFF (GMU_OFF + LDIM)    // 1318688

__device__ __forceinline__ float wsum(float v) {
#pragma unroll
  for (int m = 1; m < 64; m <<= 1) v += __shfl_xor(v, m, 64);
  return v;
}
__device__ __forceinline__ void wsum2(float& a, float& b) {
#pragma unroll
  for (int m = 1; m < 64; m <<= 1) {
    a += __shfl_xor(a, m, 64);
    b += __shfl_xor(b, m, 64);
  }
}
__device__ __forceinline__ void wsum4(float& a, float& b, float& c, float& d) {
#pragma unroll
  for (int m = 1; m < 64; m <<= 1) {
    a += __shfl_xor(a, m, 64);
    b += __shfl_xor(b, m, 64);
    c += __shfl_xor(c, m, 64);
    d += __shfl_xor(d, m, 64);
  }
}
__device__ __forceinline__ float lnorm64(float x, float g, float b) {
  float s1 = x, s2 = x * x;
  wsum2(s1, s2);
  float mu = s1 * (1.0f / 64.0f);
  float var = fmaf(-mu, mu, s2 * (1.0f / 64.0f));
  return (x - mu) * rsqrtf(var + 1e-5f) * g + b;
}
__device__ __forceinline__ void cp4(float* dst, const float* __restrict__ src,
                                    int n4, int t) {
  const float4* s4 = (const float4*)src;
  float4* d4 = (float4*)dst;
  for (int e = t; e < n4; e += 256) d4[e] = s4[e];
}

// ---------------- GATv2 gather, QUARTER-wave-split: wave h handles j in [16h,16h+16) ----------------
// of each 64-edge batch; partials combined by caller via LDS. Self-loop appended by h==3.
__device__ __forceinline__ void gat_gather_q(
    const int* __restrict__ cnt, const unsigned short* __restrict__ slot,
    const float* __restrict__ xl, float xri, float ak, int i, int k, int h,
    float& accO, float& denO) {
  int n = min(cnt[i], CAP);
  const unsigned short* srow = slot + i * CAP;
  float acc = 0.f, den = 0.f;
  for (int e0 = 0; e0 < n; e0 += 64) {
    int sidx = (e0 + k < n) ? (int)srow[e0 + k] : 0;   // 64 srcs, 128B coalesced
    int nn = min(64, n - e0);
    int jbeg = h * 16;
    int jend = min(nn, jbeg + 16);
    int j = jbeg;
    for (; j + 3 < jend; j += 4) {
      int s0 = __shfl(sidx, j, 64),     s1 = __shfl(sidx, j + 1, 64);
      int s2 = __shfl(sidx, j + 2, 64), s3 = __shfl(sidx, j + 3, 64);
      float x0 = xl[s0 * HD + k], x1 = xl[s1 * HD + k];
      float x2 = xl[s2 * HD + k], x3 = xl[s3 * HD + k];
      float e0v = x0 + xri, e1v = x1 + xri, e2v = x2 + xri, e3v = x3 + xri;
      e0v = fmaxf(e0v, 0.2f * e0v);
      e1v = fmaxf(e1v, 0.2f * e1v);
      e2v = fmaxf(e2v, 0.2f * e2v);
      e3v = fmaxf(e3v, 0.2f * e3v);
      float p0 = e0v * ak, p1 = e1v * ak, p2 = e2v * ak, p3 = e3v * ak;
      wsum4(p0, p1, p2, p3);
      float w0 = expf(p0), w1 = expf(p1), w2 = expf(p2), w3 = expf(p3);
      acc = fmaf(w0, x0, acc); den += w0;
      acc = fmaf(w1, x1, acc); den += w1;
      acc = fmaf(w2, x2, acc); den += w2;
      acc = fmaf(w3, x3, acc); den += w3;
    }
    for (; j < jend; ++j) {
      int s0 = __shfl(sidx, j, 64);
      float x0 = xl[s0 * HD + k];
      float e0v = x0 + xri;
      e0v = fmaxf(e0v, 0.2f * e0v);
      float w0 = expf(wsum(e0v * ak));
      acc = fmaf(w0, x0, acc); den += w0;
    }
  }
  if (h == 3) {   // self loop, appended last
    float xs = xl[i * HD + k];
    float es = xs + xri;
    es = fmaxf(es, 0.2f * es);
    float ws = expf(wsum(es * ak));
    acc = fmaf(ws, xs, acc); den += ws;
  }
  accO = acc; denO = den;
}

// ---------------- layer-1 transform + inline padded-CSR build (slot=u16) ----------------
__global__ __launch_bounds__(256) void gvae_xform1(
    const float* __restrict__ in,
    const float* __restrict__ Wl, const float* __restrict__ bl,
    const float* __restrict__ Wr, const float* __restrict__ br,
    float* __restrict__ xl, float* __restrict__ xr,
    const int* __restrict__ ei, int* __restrict__ cnt,
    unsigned short* __restrict__ slot) {
  __shared__ __align__(16) float sWl[FIN * HD];
  __shared__ __align__(16) float sWr[FIN * HD];
  int t = threadIdx.x;
  int gid = blockIdx.x * 256 + t;
  if (gid < NE) {
    int d = ei[NE + gid];
    int c = atomicAdd(&cnt[d], 1);
    if (c < CAP) slot[d * CAP + c] = (unsigned short)ei[gid];
  }
  cp4(sWl, Wl, FIN * 16, t);
  cp4(sWr, Wr, FIN * 16, t);
  int i = blockIdx.x * 4 + (t >> 6);
  int k = t & 63;
  float xv = (k < FIN) ? in[i * FIN + k] : 0.f;
  float l0 = bl[k], l1 = 0.f, r0 = br[k], r1 = 0.f;
  __syncthreads();
#pragma unroll
  for (int a = 0; a < FIN; a += 2) {
    float xa = __shfl(xv, a, 64);
    l0 = fmaf(xa, sWl[a * HD + k], l0);
    r0 = fmaf(xa, sWr[a * HD + k], r0);
    if (a + 1 < FIN) {
      float xb = __shfl(xv, a + 1, 64);
      l1 = fmaf(xb, sWl[(a + 1) * HD + k], l1);
      r1 = fmaf(xb, sWr[(a + 1) * HD + k], r1);
    }
  }
  xl[i * HD + k] = l0 + l1;
  xr[i * HD + k] = r0 + r1;
}

// ---------------- fused GAT-1 gather (4 waves/node) + layer-2 transform ----------------
// 512-thread blocks: 8 waves = 2 nodes x 4 quarters. Post-gather: h=0 -> xlo, h=1 -> xro.
__global__ __launch_bounds__(512, 4) void gvae_gatherx(
    const int* __restrict__ cnt, const unsigned short* __restrict__ slot,
    const float* __restrict__ xl, const float* __restrict__ xr,
    const float* __restrict__ att, const float* __restrict__ hbias,
    const float* __restrict__ Wl, const float* __restrict__ bl,
    const float* __restrict__ Wr, const float* __restrict__ br,
    float* __restrict__ xlo, float* __restrict__ xro) {
  __shared__ float sA[2][4][64];
  __shared__ float sD[2][4][64];
  int t = threadIdx.x;
  int wv = t >> 6, k = t & 63;
  int p = wv >> 2, h = wv & 3;
  int i = blockIdx.x * 2 + p;
  float xri = xr[i * HD + k];
  float ak = att[k];
  float pa, pd;
  gat_gather_q(cnt, slot, xl, xri, ak, i, k, h, pa, pd);
  sA[p][h][k] = pa;
  sD[p][h][k] = pd;
  __syncthreads();
  if (h < 2) {
    float num = ((sA[p][0][k] + sA[p][1][k]) + sA[p][2][k]) + sA[p][3][k];
    float den = ((sD[p][0][k] + sD[p][1][k]) + sD[p][2][k]) + sD[p][3][k];
    float hv = fmaxf(num / den + hbias[k], 0.f);
    const float* W = h ? Wr : Wl;
    float c0 = h ? br[k] : bl[k];
    float c1 = 0.f, c2 = 0.f, c3 = 0.f;
#pragma unroll
    for (int a = 0; a < HD; a += 4) {
      c0 = fmaf(__shfl(hv, a, 64),     W[a * HD + k],       c0);
      c1 = fmaf(__shfl(hv, a + 1, 64), W[(a + 1) * HD + k], c1);
      c2 = fmaf(__shfl(hv, a + 2, 64), W[(a + 2) * HD + k], c2);
      c3 = fmaf(__shfl(hv, a + 3, 64), W[(a + 3) * HD + k], c3);
    }
    float r = (c0 + c1) + (c2 + c3);
    if (h == 0) xlo[i * HD + k] = r;
    else        xro[i * HD + k] = r;
  }
}

// ---------------- GAT-2 gather (4 waves/node) + encoder head ----------------
// Post-gather: wave h=0: mu/logvar + z; wave h=1: u/v GEMVs (z via LDS).
__global__ __launch_bounds__(512, 4) void gvae_node(
    const int* __restrict__ cnt, const unsigned short* __restrict__ slot,
    const float* __restrict__ xl, const float* __restrict__ xr,
    const float* __restrict__ att, const float* __restrict__ bias2,
    const float* __restrict__ eps,
    const float* __restrict__ Wnm, const float* __restrict__ bnm,
    const float* __restrict__ Wnv, const float* __restrict__ bnv,
    const float* __restrict__ We1, const float* __restrict__ be1,
    float* __restrict__ uo, float* __restrict__ vo,
    float* __restrict__ h2o, float* __restrict__ zzo,
    float* __restrict__ gh, float* __restrict__ out) {
  __shared__ float sA[2][4][64];
  __shared__ float sD[2][4][64];
  __shared__ float sZ[2][32];
  __shared__ float ghred[128];
  int t = threadIdx.x;
  int wv = t >> 6, k = t & 63;
  int p = wv >> 2, h = wv & 3;
  int i = blockIdx.x * 2 + p;
  int kk = k & 31;

  float xri = xr[i * HD + k];
  float ak = att[k];
  float pa, pd;
  gat_gather_q(cnt, slot, xl, xri, ak, i, k, h, pa, pd);
  sA[p][h][k] = pa;
  sD[p][h][k] = pd;
  __syncthreads();
  float h2k = 0.f;
  if (h == 0) {
    float num = ((sA[p][0][k] + sA[p][1][k]) + sA[p][2][k]) + sA[p][3][k];
    float den = ((sD[p][0][k] + sD[p][1][k]) + sD[p][2][k]) + sD[p][3][k];
    h2k = fmaxf(num / den + bias2[k], 0.f);
    h2o[i * HD + k] = h2k;
    ghred[p * 64 + k] = h2k;
  }
  __syncthreads();
  if (t < 64) {               // one atomic per block per k (2 nodes summed)
    float s = ghred[t] + ghred[t + 64];
    atomicAdd(&gh[t], s * (1.0f / NN));
  }

  if (h == 0) {
    // node_mu (lanes 0..31) / node_logvar (lanes 32..63)
    const float* W = (k < 32) ? Wnm : Wnv;
    float c0 = (k < 32) ? bnm[kk] : bnv[kk];
    float c1 = 0.f, c2 = 0.f, c3 = 0.f;
#pragma unroll
    for (int a = 0; a < HD; a += 4) {
      c0 = fmaf(__shfl(h2k, a, 64),     W[a * LDIM + kk],       c0);
      c1 = fmaf(__shfl(h2k, a + 1, 64), W[(a + 1) * LDIM + kk], c1);
      c2 = fmaf(__shfl(h2k, a + 2, 64), W[(a + 2) * LDIM + kk], c2);
      c3 = fmaf(__shfl(h2k, a + 3, 64), W[(a + 3) * LDIM + kk], c3);
    }
    float acc = (c0 + c1) + (c2 + c3);
    if (k < 32) out[MU_OFF + i * LDIM + kk] = acc;
    else        out[LV_OFF + i * LDIM + kk] = acc;

    // z = mu + eps * exp(0.5*logvar)  (valid lanes 0..31)
    float lv = __shfl(acc, k + 32, 64);
    float zk = acc + eps[i * LDIM + kk] * expf(0.5f * lv);
    if (k < 32) {
      zzo[i * LDIM + kk] = zk;
      sZ[p][kk] = zk;
    }
  }
  __syncthreads();
  if (h == 1) {
    // u = z@We1[:32] + be1 ; v = z@We1[32:]
    float zk = sZ[p][kk];
    float u0 = be1[k], u1 = 0.f, v0 = 0.f, v1 = 0.f;
#pragma unroll
    for (int a = 0; a < LDIM; a += 2) {
      float za = __shfl(zk, a, 64);
      float zb = __shfl(zk, a + 1, 64);
      u0 = fmaf(za, We1[a * HD + k], u0);
      u1 = fmaf(zb, We1[(a + 1) * HD + k], u1);
      v0 = fmaf(za, We1[(a + LDIM) * HD + k], v0);
      v1 = fmaf(zb, We1[(a + 1 + LDIM) * HD + k], v1);
    }
    uo[i * HD + k] = u0 + u1;
    vo[i * HD + k] = v0 + v1;
  }
}

// ---------------- edge tiles (1200 x 16x64, U in registers) + decoder blocks + graph head ----------------
__global__ __launch_bounds__(256) void gvae_edge(
    const float* __restrict__ u, const float* __restrict__ v,
    const float* __restrict__ lng, const float* __restrict__ lnb,
    const float* __restrict__ w2, const float* __restrict__ be2,
    const float* __restrict__ gh,
    const float* __restrict__ Wgm, const float* __restrict__ bgm,
    const float* __restrict__ Wgv, const float* __restrict__ bgv,
    const float* __restrict__ h2, const float* __restrict__ zz,
    const float* __restrict__ Wd1, const float* __restrict__ bd1,
    const float* __restrict__ g1, const float* __restrict__ b1,
    const float* __restrict__ Wd2, const float* __restrict__ bd2,
    const float* __restrict__ g2, const float* __restrict__ b2,
    const float* __restrict__ Wd3, const float* __restrict__ bd3,
    const float* __restrict__ Wf1, const float* __restrict__ bf1,
    const float* __restrict__ gf, const float* __restrict__ bfv,
    const float* __restrict__ Wf2, const float* __restrict__ bf2,
    float* __restrict__ out) {
  __shared__ float V[64 * 68];
  __shared__ float C[64];
  __shared__ float cc[2];
  int t = threadIdx.x;
  int b = blockIdx.x;
  int wv = t >> 6, lane = t & 63;

  if (b >= NTILE) {
    // ============ decoder block: 4 nodes, 1 wave each ============
    int i = (b - NTILE) * 4 + wv;
    int k = lane;
    int kc = (k < FIN) ? k : (FIN - 1);
    float h2k = h2[i * HD + k];
    float zk = zz[i * LDIM + (k & 31)];

    float c0 = bd1[k], c1 = 0.f, c2 = 0.f, c3 = 0.f;
#pragma unroll
    for (int a = 0; a < LDIM; a += 4) {
      c0 = fmaf(__shfl(zk, a, 64),     Wd1[a * HD + k],       c0);
      c1 = fmaf(__shfl(zk, a + 1, 64), Wd1[(a + 1) * HD + k], c1);
      c2 = fmaf(__shfl(zk, a + 2, 64), Wd1[(a + 2) * HD + k], c2);
      c3 = fmaf(__shfl(zk, a + 3, 64), Wd1[(a + 3) * HD + k], c3);
    }
    float nf1 = lnorm64(fmaxf((c0 + c1) + (c2 + c3), 0.f), g1[k], b1[k]);

    c0 = bd2[k]; c1 = 0.f; c2 = 0.f; c3 = 0.f;
#pragma unroll
    for (int a = 0; a < HD; a += 4) {
      c0 = fmaf(__shfl(nf1, a, 64),     Wd2[a * HD + k],       c0);
      c1 = fmaf(__shfl(nf1, a + 1, 64), Wd2[(a + 1) * HD + k], c1);
      c2 = fmaf(__shfl(nf1, a + 2, 64), Wd2[(a + 2) * HD + k], c2);
      c3 = fmaf(__shfl(nf1, a + 3, 64), Wd2[(a + 3) * HD + k], c3);
    }
    float nf2 = lnorm64(fmaxf((c0 + c1) + (c2 + c3), 0.f), g2[k], b2[k]);

    c0 = 0.f; c1 = 0.f; c2 = 0.f; c3 = 0.f;
#pragma unroll
    for (int a = 0; a < HD; a += 4) {
      c0 = fmaf(__shfl(nf2, a, 64),     Wd3[a * FIN + kc],       c0);
      c1 = fmaf(__shfl(nf2, a + 1, 64), Wd3[(a + 1) * FIN + kc], c1);
      c2 = fmaf(__shfl(nf2, a + 2, 64), Wd3[(a + 2) * FIN + kc], c2);
      c3 = fmaf(__shfl(nf2, a + 3, 64), Wd3[(a + 3) * FIN + kc], c3);
    }
    float nf3 = (k < FIN) ? ((c0 + c1) + (c2 + c3) + bd3[kc]) : 0.f;

    c0 = bf1[k]; c1 = 0.f; c2 = 0.f; c3 = 0.f;
#pragma unroll
    for (int j = 0; j < FIN; j++) {
      float nj = __shfl(nf3, j, 64);
      c0 = fmaf(nj, Wf1[j * HD + k], c0);
    }
#pragma unroll
    for (int a = 0; a < HD; a += 4) {
      c0 = fmaf(__shfl(h2k, a, 64),     Wf1[(FIN + a) * HD + k],     c0);
      c1 = fmaf(__shfl(h2k, a + 1, 64), Wf1[(FIN + a + 1) * HD + k], c1);
      c2 = fmaf(__shfl(h2k, a + 2, 64), Wf1[(FIN + a + 2) * HD + k], c2);
      c3 = fmaf(__shfl(h2k, a + 3, 64), Wf1[(FIN + a + 3) * HD + k], c3);
    }
    float rr = lnorm64(fmaxf((c0 + c1) + (c2 + c3), 0.f), gf[k], bfv[k]);

    c0 = 0.f; c1 = 0.f; c2 = 0.f; c3 = 0.f;
#pragma unroll
    for (int a = 0; a < HD; a += 4) {
      c0 = fmaf(__shfl(rr, a, 64),     Wf2[a * FIN + kc],       c0);
      c1 = fmaf(__shfl(rr, a + 1, 64), Wf2[(a + 1) * FIN + kc], c1);
      c2 = fmaf(__shfl(rr, a + 2, 64), Wf2[(a + 2) * FIN + kc], c2);
      c3 = fmaf(__shfl(rr, a + 3, 64), Wf2[(a + 3) * FIN + kc], c3);
    }
    if (k < FIN) out[i * FIN + k] = (c0 + c1) + (c2 + c3) + bf2[kc];
    return;
  }

  // ============ tile block: 16 rows x 64 cols ============
  if (b == 0 && wv == 3) {   // fused graph head
    int kk = lane & 31;
    float ghk = gh[lane];
    const float* W = (lane < 32) ? Wgm : Wgv;
    float c0 = (lane < 32) ? bgm[kk] : bgv[kk];
    float c1 = 0.f, c2 = 0.f, c3 = 0.f;
#pragma unroll
    for (int a = 0; a < HD; a += 4) {
      c0 = fmaf(__shfl(ghk, a, 64),     W[a * LDIM + kk],       c0);
      c1 = fmaf(__shfl(ghk, a + 1, 64), W[(a + 1) * LDIM + kk], c1);
      c2 = fmaf(__shfl(ghk, a + 2, 64), W[(a + 2) * LDIM + kk], c2);
      c3 = fmaf(__shfl(ghk, a + 3, 64), W[(a + 3) * LDIM + kk], c3);
    }
    float acc = (c0 + c1) + (c2 + c3);
    if (lane < 32) out[GMU_OFF + kk] = acc;
    else           out[GLV_OFF + kk] = acc;
  }

  int rem = b, cg = 0;
  while (rem >= 4 * (cg + 1)) { rem -= 4 * (cg + 1); cg++; }
  int rg = rem;

  float Ureg[4];
#pragma unroll
  for (int q = 0; q < 4; ++q)
    Ureg[q] = u[(rg * 16 + wv * 4 + q) * HD + lane];

  const float4* v4p = (const float4*)(v + cg * 64 * HD);
#pragma unroll
  for (int it = 0; it < 4; ++it) {
    int r = t + it * 256;
    int row = r >> 4, q = r & 15;
    float4 vv = v4p[r];
    *(float4*)&V[row * 68 + q * 4] = vv;
  }
  if (t < 64) {
    float ck = lng[t] * w2[t];
    C[t] = ck;
    float cb = lnb[t] * w2[t];
    float sC = wsum(ck);
    float sB = wsum(cb);
    if (t == 0) { cc[0] = sC; cc[1] = sB + be2[0]; }
  }
  __syncthreads();
  float C1 = cc[0], C0 = cc[1];

  float S1[4], S2[4], Sc[4];
#pragma unroll
  for (int q = 0; q < 4; q++) { S1[q] = 0.f; S2[q] = 0.f; Sc[q] = 0.f; }
  for (int k4 = 0; k4 < 16; k4++) {
    float4 v4 = *(const float4*)&V[lane * 68 + k4 * 4];
    float4 c4 = *(const float4*)&C[k4 * 4];
#pragma unroll
    for (int q = 0; q < 4; q++) {
      float u0 = __shfl(Ureg[q], k4 * 4, 64);
      float u1 = __shfl(Ureg[q], k4 * 4 + 1, 64);
      float u2 = __shfl(Ureg[q], k4 * 4 + 2, 64);
      float u3 = __shfl(Ureg[q], k4 * 4 + 3, 64);
      float t0 = fmaxf(u0 + v4.x, 0.f);
      float t1 = fmaxf(u1 + v4.y, 0.f);
      float t2 = fmaxf(u2 + v4.z, 0.f);
      float t3 = fmaxf(u3 + v4.w, 0.f);
      S1[q] += (t0 + t1) + (t2 + t3);
      S2[q] = fmaf(t0, t0, fmaf(t1, t1, fmaf(t2, t2, fmaf(t3, t3, S2[q]))));
      Sc[q] = fmaf(t0, c4.x, fmaf(t1, c4.y, fmaf(t2, c4.z, fmaf(t3, c4.w, Sc[q]))));
    }
  }
  int j = cg * 64 + lane;
  const float inv64 = 1.0f / 64.0f;
#pragma unroll
  for (int q = 0; q < 4; q++) {
    int i = rg * 16 + wv * 4 + q;
    if (j > i) {
      int pbase = i * (2 * NN - i - 1) / 2 - i - 1;
      float mu = S1[q] * inv64;
      float var = fmaf(-mu, mu, S2[q] * inv64);
      float logit = (Sc[q] - mu * C1) * rsqrtf(var + 1e-5f) + C0;
      out[EL_OFF + pbase + j] = logit;
    }
  }
}

extern "C" void kernel_launch(void* const* d_in, const int* in_sizes, int n_in,
                              void* d_out, int out_size, void* d_ws, size_t ws_size,
                              hipStream_t stream) {
  const float* x    = (const float*)d_in[0];
  const int*   ei   = (const int*)d_in[1];
  const float* eps  = (const float*)d_in[2];
  // d_in[3] = eps_graph: z_graph computed but unused downstream -> skip
  const float* Wl1  = (const float*)d_in[4];
  const float* bl1  = (const float*)d_in[5];
  const float* Wr1  = (const float*)d_in[6];
  const float* br1  = (const float*)d_in[7];
  const float* att1 = (const float*)d_in[8];
  const float* bias1= (const float*)d_in[9];
  const float* Wl2  = (const float*)d_in[10];
  const float* bl2  = (const float*)d_in[11];
  const float* Wr2  = (const float*)d_in[12];
  const float* br2  = (const float*)d_in[13];
  const float* att2 = (const float*)d_in[14];
  const float* bias2= (const float*)d_in[15];
  const float* Wnm  = (const float*)d_in[16];
  const float* bnm  = (const float*)d_in[17];
  const float* Wnv  = (const float*)d_in[18];
  const float* bnv  = (const float*)d_in[19];
  const float* Wgm  = (const float*)d_in[20];
  const float* bgm  = (const float*)d_in[21];
  const float* Wgv  = (const float*)d_in[22];
  const float* bgv  = (const float*)d_in[23];
  const float* Wd1  = (const float*)d_in[24];
  const float* bd1  = (const float*)d_in[25];
  const float* ln1g = (const float*)d_in[26];
  const float* ln1b = (const float*)d_in[27];
  const float* Wd2  = (const float*)d_in[28];
  const float* bd2  = (const float*)d_in[29];
  const float* ln2g = (const float*)d_in[30];
  const float* ln2b = (const float*)d_in[31];
  const float* Wd3  = (const float*)d_in[32];
  const float* bd3  = (const float*)d_in[33];
  const float* We1  = (const float*)d_in[34];
  const float* be1  = (const float*)d_in[35];
  const float* lneg = (const float*)d_in[36];
  const float* lneb = (const float*)d_in[37];
  const float* We2  = (const float*)d_in[38];
  const float* be2  = (const float*)d_in[39];
  const float* Wf1  = (const float*)d_in[40];
  const float* bf1  = (const float*)d_in[41];
  const float* lnfg = (const float*)d_in[42];
  const float* lnfb = (const float*)d_in[43];
  const float* Wf2  = (const float*)d_in[44];
  const float* bf2  = (const float*)d_in[45];
  float* out = (float*)d_out;

  // workspace layout
  float* fb  = (float*)d_ws;
  float* xl1 = fb;
  float* xr1 = xl1 + NN * HD;
  float* xl2 = xr1 + NN * HD;
  float* xr2 = xl2 + NN * HD;
  float* uu  = xr2 + NN * HD;
  float* vv  = uu  + NN * HD;
  float* h2  = vv  + NN * HD;          // NN*64
  float* zz  = h2  + NN * HD;          // NN*32
  float* gh  = zz  + NN * LDIM;        // 64 floats (zeroed)
  int* cnt    = (int*)(gh + HD);       // NN ints (zeroed)
  unsigned short* slot = (unsigned short*)(cnt + NN);  // NN*CAP u16 (bounded by cnt)

  // zero gh + cnt (contiguous, 1600 dwords)
  hipMemsetAsync(gh, 0, (HD + NN) * sizeof(float), stream);

  gvae_xform1<<<NN / 4, 256, 0, stream>>>(x, Wl1, bl1, Wr1, br1, xl1, xr1,
                                          ei, cnt, slot);
  gvae_gatherx<<<NN / 2, 512, 0, stream>>>(cnt, slot, xl1, xr1, att1, bias1,
                                           Wl2, bl2, Wr2, br2, xl2, xr2);
  gvae_node<<<NN / 2, 512, 0, stream>>>(cnt, slot, xl2, xr2, att2, bias2, eps,
      Wnm, bnm, Wnv, bnv, We1, be1,
      uu, vv, h2, zz, gh, out);
  gvae_edge<<<NTILE + NN / 4, 256, 0, stream>>>(uu, vv, lneg, lneb, We2, be2,
      gh, Wgm, bgm, Wgv, bgv,
      h2, zz,
      Wd1, bd1, ln1g, ln1b, Wd2, bd2, ln2g, ln2b, Wd3, bd3,
      Wf1, bf1, lnfg, lnfb, Wf2, bf2,
      out);
}

// Round 10
// 212.850 us; speedup vs baseline: 1.0668x; 1.0668x over previous
//
#include <hip/hip_runtime.h>

#define NN 1536
#define NE 49152
#define FIN 27
#define HD 64
#define LDIM 32
#define PP 1178880        // NN*(NN-1)/2
#define CAP 128           // padded-CSR row capacity (in-deg ~Poisson(32); passed at 128)
#define NTILE 1200        // 16x64 upper-tri tiles: sum_{cg=0..23} 4*(cg+1)

#define EL_OFF  (NN*FIN)            // 41472
#define MU_OFF  (EL_OFF + PP)       // 1220352
#define LV_OFF  (MU_OFF + NN*LDIM)  // 1269504
#define GMU_OFF (LV_OFF + NN*LDIM)  // 1318656
#define GLV_OFF (GMU_OFF + LDIM)    // 1318688

__device__ __forceinline__ float wsum(float v) {
#pragma unroll
  for (int m = 1; m < 64; m <<= 1) v += __shfl_xor(v, m, 64);
  return v;
}
__device__ __forceinline__ void wsum2(float& a, float& b) {
#pragma unroll
  for (int m = 1; m < 64; m <<= 1) {
    a += __shfl_xor(a, m, 64);
    b += __shfl_xor(b, m, 64);
  }
}
__device__ __forceinline__ void wsum4(float& a, float& b, float& c, float& d) {
#pragma unroll
  for (int m = 1; m < 64; m <<= 1) {
    a += __shfl_xor(a, m, 64);
    b += __shfl_xor(b, m, 64);
    c += __shfl_xor(c, m, 64);
    d += __shfl_xor(d, m, 64);
  }
}
__device__ __forceinline__ float lnorm64(float x, float g, float b) {
  float s1 = x, s2 = x * x;
  wsum2(s1, s2);
  float mu = s1 * (1.0f / 64.0f);
  float var = fmaf(-mu, mu, s2 * (1.0f / 64.0f));
  return (x - mu) * rsqrtf(var + 1e-5f) * g + b;
}
__device__ __forceinline__ void cp4(float* dst, const float* __restrict__ src,
                                    int n4, int t) {
  const float4* s4 = (const float4*)src;
  float4* d4 = (float4*)dst;
  for (int e = t; e < n4; e += 256) d4[e] = s4[e];
}

// ---------------- GATv2 gather, HALF-wave-split (r8-exact): wave h handles ----------------
// j in [32h,32h+32) of each 64-edge batch; partials combined via LDS. Self-loop by h==1.
__device__ __forceinline__ void gat_gather_half(
    const int* __restrict__ cnt, const unsigned short* __restrict__ slot,
    const float* __restrict__ xl, float xri, float ak, int i, int k, int h,
    float& accO, float& denO) {
  int n = min(cnt[i], CAP);
  const unsigned short* srow = slot + i * CAP;
  float acc = 0.f, den = 0.f;
  for (int e0 = 0; e0 < n; e0 += 64) {
    int sidx = (e0 + k < n) ? (int)srow[e0 + k] : 0;   // 64 srcs, 128B coalesced
    int nn = min(64, n - e0);
    int jbeg = h * 32;
    int jend = min(nn, jbeg + 32);
    int j = jbeg;
    for (; j + 3 < jend; j += 4) {
      int s0 = __shfl(sidx, j, 64),     s1 = __shfl(sidx, j + 1, 64);
      int s2 = __shfl(sidx, j + 2, 64), s3 = __shfl(sidx, j + 3, 64);
      float x0 = xl[s0 * HD + k], x1 = xl[s1 * HD + k];
      float x2 = xl[s2 * HD + k], x3 = xl[s3 * HD + k];
      float e0v = x0 + xri, e1v = x1 + xri, e2v = x2 + xri, e3v = x3 + xri;
      e0v = fmaxf(e0v, 0.2f * e0v);
      e1v = fmaxf(e1v, 0.2f * e1v);
      e2v = fmaxf(e2v, 0.2f * e2v);
      e3v = fmaxf(e3v, 0.2f * e3v);
      float p0 = e0v * ak, p1 = e1v * ak, p2 = e2v * ak, p3 = e3v * ak;
      wsum4(p0, p1, p2, p3);
      float w0 = expf(p0), w1 = expf(p1), w2 = expf(p2), w3 = expf(p3);
      acc = fmaf(w0, x0, acc); den += w0;
      acc = fmaf(w1, x1, acc); den += w1;
      acc = fmaf(w2, x2, acc); den += w2;
      acc = fmaf(w3, x3, acc); den += w3;
    }
    for (; j < jend; ++j) {
      int s0 = __shfl(sidx, j, 64);
      float x0 = xl[s0 * HD + k];
      float e0v = x0 + xri;
      e0v = fmaxf(e0v, 0.2f * e0v);
      float w0 = expf(wsum(e0v * ak));
      acc = fmaf(w0, x0, acc); den += w0;
    }
  }
  if (h == 1) {   // self loop, appended last
    float xs = xl[i * HD + k];
    float es = xs + xri;
    es = fmaxf(es, 0.2f * es);
    float ws = expf(wsum(es * ak));
    acc = fmaf(ws, xs, acc); den += ws;
  }
  accO = acc; denO = den;
}

// ---------------- layer-1 transform + inline padded-CSR build (slot=u16) ----------------
__global__ __launch_bounds__(256) void gvae_xform1(
    const float* __restrict__ in,
    const float* __restrict__ Wl, const float* __restrict__ bl,
    const float* __restrict__ Wr, const float* __restrict__ br,
    float* __restrict__ xl, float* __restrict__ xr,
    const int* __restrict__ ei, int* __restrict__ cnt,
    unsigned short* __restrict__ slot) {
  __shared__ __align__(16) float sWl[FIN * HD];
  __shared__ __align__(16) float sWr[FIN * HD];
  int t = threadIdx.x;
  int gid = blockIdx.x * 256 + t;
  if (gid < NE) {
    int d = ei[NE + gid];
    int c = atomicAdd(&cnt[d], 1);
    if (c < CAP) slot[d * CAP + c] = (unsigned short)ei[gid];
  }
  cp4(sWl, Wl, FIN * 16, t);
  cp4(sWr, Wr, FIN * 16, t);
  int i = blockIdx.x * 4 + (t >> 6);
  int k = t & 63;
  float xv = (k < FIN) ? in[i * FIN + k] : 0.f;
  float l0 = bl[k], l1 = 0.f, r0 = br[k], r1 = 0.f;
  __syncthreads();
#pragma unroll
  for (int a = 0; a < FIN; a += 2) {
    float xa = __shfl(xv, a, 64);
    l0 = fmaf(xa, sWl[a * HD + k], l0);
    r0 = fmaf(xa, sWr[a * HD + k], r0);
    if (a + 1 < FIN) {
      float xb = __shfl(xv, a + 1, 64);
      l1 = fmaf(xb, sWl[(a + 1) * HD + k], l1);
      r1 = fmaf(xb, sWr[(a + 1) * HD + k], r1);
    }
  }
  xl[i * HD + k] = l0 + l1;
  xr[i * HD + k] = r0 + r1;
}

// ---------------- fused GAT-1 gather (2 waves/node) + layer-2 transform (r8-exact) ----------------
__global__ __launch_bounds__(512, 4) void gvae_gatherx(
    const int* __restrict__ cnt, const unsigned short* __restrict__ slot,
    const float* __restrict__ xl, const float* __restrict__ xr,
    const float* __restrict__ att, const float* __restrict__ hbias,
    const float* __restrict__ Wl, const float* __restrict__ bl,
    const float* __restrict__ Wr, const float* __restrict__ br,
    float* __restrict__ xlo, float* __restrict__ xro) {
  __shared__ float sA[4][2][64];
  __shared__ float sD[4][2][64];
  int t = threadIdx.x;
  int wv = t >> 6, k = t & 63;
  int p = wv >> 1, h = wv & 1;
  int i = blockIdx.x * 4 + p;
  float xri = xr[i * HD + k];
  float ak = att[k];
  float pa, pd;
  gat_gather_half(cnt, slot, xl, xri, ak, i, k, h, pa, pd);
  sA[p][h][k] = pa;
  sD[p][h][k] = pd;
  __syncthreads();
  float hv = fmaxf((sA[p][0][k] + sA[p][1][k]) / (sD[p][0][k] + sD[p][1][k])
                   + hbias[k], 0.f);
  const float* W = h ? Wr : Wl;
  float c0 = h ? br[k] : bl[k];
  float c1 = 0.f, c2 = 0.f, c3 = 0.f;
#pragma unroll
  for (int a = 0; a < HD; a += 4) {
    c0 = fmaf(__shfl(hv, a, 64),     W[a * HD + k],       c0);
    c1 = fmaf(__shfl(hv, a + 1, 64), W[(a + 1) * HD + k], c1);
    c2 = fmaf(__shfl(hv, a + 2, 64), W[(a + 2) * HD + k], c2);
    c3 = fmaf(__shfl(hv, a + 3, 64), W[(a + 3) * HD + k], c3);
  }
  float r = (c0 + c1) + (c2 + c3);
  if (h == 0) xlo[i * HD + k] = r;
  else        xro[i * HD + k] = r;
}

// ---------------- GAT-2 gather (2 waves/node) + encoder head (r8-exact) ----------------
__global__ __launch_bounds__(512, 4) void gvae_node(
    const int* __restrict__ cnt, const unsigned short* __restrict__ slot,
    const float* __restrict__ xl, const float* __restrict__ xr,
    const float* __restrict__ att, const float* __restrict__ bias2,
    const float* __restrict__ eps,
    const float* __restrict__ Wnm, const float* __restrict__ bnm,
    const float* __restrict__ Wnv, const float* __restrict__ bnv,
    const float* __restrict__ We1, const float* __restrict__ be1,
    float* __restrict__ uo, float* __restrict__ vo,
    float* __restrict__ h2o, float* __restrict__ zzo,
    float* __restrict__ gh, float* __restrict__ out) {
  __shared__ float sA[4][2][64];
  __shared__ float sD[4][2][64];
  __shared__ float sZ[4][32];
  __shared__ float ghred[256];
  int t = threadIdx.x;
  int wv = t >> 6, k = t & 63;
  int p = wv >> 1, h = wv & 1;
  int i = blockIdx.x * 4 + p;
  int kk = k & 31;

  float xri = xr[i * HD + k];
  float ak = att[k];
  float pa, pd;
  gat_gather_half(cnt, slot, xl, xri, ak, i, k, h, pa, pd);
  sA[p][h][k] = pa;
  sD[p][h][k] = pd;
  __syncthreads();
  float h2k = fmaxf((sA[p][0][k] + sA[p][1][k]) / (sD[p][0][k] + sD[p][1][k])
                    + bias2[k], 0.f);
  if (h == 0) {
    h2o[i * HD + k] = h2k;
    ghred[p * 64 + k] = h2k;
  }
  __syncthreads();
  if (t < 64) {               // one atomic per block per k (4 nodes summed)
    float s = (ghred[t] + ghred[t + 64]) + (ghred[t + 128] + ghred[t + 192]);
    atomicAdd(&gh[t], s * (1.0f / NN));
  }

  if (h == 0) {
    // node_mu (lanes 0..31) / node_logvar (lanes 32..63)
    const float* W = (k < 32) ? Wnm : Wnv;
    float c0 = (k < 32) ? bnm[kk] : bnv[kk];
    float c1 = 0.f, c2 = 0.f, c3 = 0.f;
#pragma unroll
    for (int a = 0; a < HD; a += 4) {
      c0 = fmaf(__shfl(h2k, a, 64),     W[a * LDIM + kk],       c0);
      c1 = fmaf(__shfl(h2k, a + 1, 64), W[(a + 1) * LDIM + kk], c1);
      c2 = fmaf(__shfl(h2k, a + 2, 64), W[(a + 2) * LDIM + kk], c2);
      c3 = fmaf(__shfl(h2k, a + 3, 64), W[(a + 3) * LDIM + kk], c3);
    }
    float acc = (c0 + c1) + (c2 + c3);
    if (k < 32) out[MU_OFF + i * LDIM + kk] = acc;
    else        out[LV_OFF + i * LDIM + kk] = acc;

    // z = mu + eps * exp(0.5*logvar)  (valid lanes 0..31)
    float lv = __shfl(acc, k + 32, 64);
    float zk = acc + eps[i * LDIM + kk] * expf(0.5f * lv);
    if (k < 32) {
      zzo[i * LDIM + kk] = zk;
      sZ[p][kk] = zk;
    }
  }
  __syncthreads();
  if (h == 1) {
    // u = z@We1[:32] + be1 ; v = z@We1[32:]
    float zk = sZ[p][kk];
    float u0 = be1[k], u1 = 0.f, v0 = 0.f, v1 = 0.f;
#pragma unroll
    for (int a = 0; a < LDIM; a += 2) {
      float za = __shfl(zk, a, 64);
      float zb = __shfl(zk, a + 1, 64);
      u0 = fmaf(za, We1[a * HD + k], u0);
      u1 = fmaf(zb, We1[(a + 1) * HD + k], u1);
      v0 = fmaf(za, We1[(a + LDIM) * HD + k], v0);
      v1 = fmaf(zb, We1[(a + 1 + LDIM) * HD + k], v1);
    }
    uo[i * HD + k] = u0 + u1;
    vo[i * HD + k] = v0 + v1;
  }
}

// ---------------- edge tiles: U staged in LDS, uniform-address broadcast reads ----------------
// Replaces 256 ds_bpermute (__shfl) per wave with 64 uniform ds_read_b128 (4x fewer
// LDS-pipe ops; same-address reads broadcast conflict-free). Math bit-identical.
__global__ __launch_bounds__(256) void gvae_edge(
    const float* __restrict__ u, const float* __restrict__ v,
    const float* __restrict__ lng, const float* __restrict__ lnb,
    const float* __restrict__ w2, const float* __restrict__ be2,
    const float* __restrict__ gh,
    const float* __restrict__ Wgm, const float* __restrict__ bgm,
    const float* __restrict__ Wgv, const float* __restrict__ bgv,
    const float* __restrict__ h2, const float* __restrict__ zz,
    const float* __restrict__ Wd1, const float* __restrict__ bd1,
    const float* __restrict__ g1, const float* __restrict__ b1,
    const float* __restrict__ Wd2, const float* __restrict__ bd2,
    const float* __restrict__ g2, const float* __restrict__ b2,
    const float* __restrict__ Wd3, const float* __restrict__ bd3,
    const float* __restrict__ Wf1, const float* __restrict__ bf1,
    const float* __restrict__ gf, const float* __restrict__ bfv,
    const float* __restrict__ Wf2, const float* __restrict__ bf2,
    float* __restrict__ out) {
  __shared__ float V[64 * 68];
  __shared__ __align__(16) float Ut[16 * 64];
  __shared__ float C[64];
  __shared__ float cc[2];
  int t = threadIdx.x;
  int b = blockIdx.x;
  int wv = t >> 6, lane = t & 63;

  if (b >= NTILE) {
    // ============ decoder block: 4 nodes, 1 wave each ============
    int i = (b - NTILE) * 4 + wv;
    int k = lane;
    int kc = (k < FIN) ? k : (FIN - 1);
    float h2k = h2[i * HD + k];
    float zk = zz[i * LDIM + (k & 31)];

    float c0 = bd1[k], c1 = 0.f, c2 = 0.f, c3 = 0.f;
#pragma unroll
    for (int a = 0; a < LDIM; a += 4) {
      c0 = fmaf(__shfl(zk, a, 64),     Wd1[a * HD + k],       c0);
      c1 = fmaf(__shfl(zk, a + 1, 64), Wd1[(a + 1) * HD + k], c1);
      c2 = fmaf(__shfl(zk, a + 2, 64), Wd1[(a + 2) * HD + k], c2);
      c3 = fmaf(__shfl(zk, a + 3, 64), Wd1[(a + 3) * HD + k], c3);
    }
    float nf1 = lnorm64(fmaxf((c0 + c1) + (c2 + c3), 0.f), g1[k], b1[k]);

    c0 = bd2[k]; c1 = 0.f; c2 = 0.f; c3 = 0.f;
#pragma unroll
    for (int a = 0; a < HD; a += 4) {
      c0 = fmaf(__shfl(nf1, a, 64),     Wd2[a * HD + k],       c0);
      c1 = fmaf(__shfl(nf1, a + 1, 64), Wd2[(a + 1) * HD + k], c1);
      c2 = fmaf(__shfl(nf1, a + 2, 64), Wd2[(a + 2) * HD + k], c2);
      c3 = fmaf(__shfl(nf1, a + 3, 64), Wd2[(a + 3) * HD + k], c3);
    }
    float nf2 = lnorm64(fmaxf((c0 + c1) + (c2 + c3), 0.f), g2[k], b2[k]);

    c0 = 0.f; c1 = 0.f; c2 = 0.f; c3 = 0.f;
#pragma unroll
    for (int a = 0; a < HD; a += 4) {
      c0 = fmaf(__shfl(nf2, a, 64),     Wd3[a * FIN + kc],       c0);
      c1 = fmaf(__shfl(nf2, a + 1, 64), Wd3[(a + 1) * FIN + kc], c1);
      c2 = fmaf(__shfl(nf2, a + 2, 64), Wd3[(a + 2) * FIN + kc], c2);
      c3 = fmaf(__shfl(nf2, a + 3, 64), Wd3[(a + 3) * FIN + kc], c3);
    }
    float nf3 = (k < FIN) ? ((c0 + c1) + (c2 + c3) + bd3[kc]) : 0.f;

    c0 = bf1[k]; c1 = 0.f; c2 = 0.f; c3 = 0.f;
#pragma unroll
    for (int j = 0; j < FIN; j++) {
      float nj = __shfl(nf3, j, 64);
      c0 = fmaf(nj, Wf1[j * HD + k], c0);
    }
#pragma unroll
    for (int a = 0; a < HD; a += 4) {
      c0 = fmaf(__shfl(h2k, a, 64),     Wf1[(FIN + a) * HD + k],     c0);
      c1 = fmaf(__shfl(h2k, a + 1, 64), Wf1[(FIN + a + 1) * HD + k], c1);
      c2 = fmaf(__shfl(h2k, a + 2, 64), Wf1[(FIN + a + 2) * HD + k], c2);
      c3 = fmaf(__shfl(h2k, a + 3, 64), Wf1[(FIN + a + 3) * HD + k], c3);
    }
    float rr = lnorm64(fmaxf((c0 + c1) + (c2 + c3), 0.f), gf[k], bfv[k]);

    c0 = 0.f; c1 = 0.f; c2 = 0.f; c3 = 0.f;
#pragma unroll
    for (int a = 0; a < HD; a += 4) {
      c0 = fmaf(__shfl(rr, a, 64),     Wf2[a * FIN + kc],       c0);
      c1 = fmaf(__shfl(rr, a + 1, 64), Wf2[(a + 1) * FIN + kc], c1);
      c2 = fmaf(__shfl(rr, a + 2, 64), Wf2[(a + 2) * FIN + kc], c2);
      c3 = fmaf(__shfl(rr, a + 3, 64), Wf2[(a + 3) * FIN + kc], c3);
    }
    if (k < FIN) out[i * FIN + k] = (c0 + c1) + (c2 + c3) + bf2[kc];
    return;
  }

  // ============ tile block: 16 rows x 64 cols ============
  if (b == 0 && wv == 3) {   // fused graph head
    int kk = lane & 31;
    float ghk = gh[lane];
    const float* W = (lane < 32) ? Wgm : Wgv;
    float c0 = (lane < 32) ? bgm[kk] : bgv[kk];
    float c1 = 0.f, c2 = 0.f, c3 = 0.f;
#pragma unroll
    for (int a = 0; a < HD; a += 4) {
      c0 = fmaf(__shfl(ghk, a, 64),     W[a * LDIM + kk],       c0);
      c1 = fmaf(__shfl(ghk, a + 1, 64), W[(a + 1) * LDIM + kk], c1);
      c2 = fmaf(__shfl(ghk, a + 2, 64), W[(a + 2) * LDIM + kk], c2);
      c3 = fmaf(__shfl(ghk, a + 3, 64), W[(a + 3) * LDIM + kk], c3);
    }
    float acc = (c0 + c1) + (c2 + c3);
    if (lane < 32) out[GMU_OFF + kk] = acc;
    else           out[GLV_OFF + kk] = acc;
  }

  int rem = b, cg = 0;
  while (rem >= 4 * (cg + 1)) { rem -= 4 * (cg + 1); cg++; }
  int rg = rem;

  // stage U (16 rows x 64 dims) into LDS for wave-uniform broadcast reads
  {
    int r = t >> 4, d4 = t & 15;
    const float4* u4p = (const float4*)(u + (rg * 16) * HD);
    *(float4*)&Ut[r * 64 + d4 * 4] = u4p[r * 16 + d4];
  }

  // stage V (64 nodes x 64 dims, stride 68) via float4
  const float4* v4p = (const float4*)(v + cg * 64 * HD);
#pragma unroll
  for (int it = 0; it < 4; ++it) {
    int r = t + it * 256;
    int row = r >> 4, q = r & 15;
    float4 vv = v4p[r];
    *(float4*)&V[row * 68 + q * 4] = vv;
  }
  if (t < 64) {
    float ck = lng[t] * w2[t];
    C[t] = ck;
    float cb = lnb[t] * w2[t];
    float sC = wsum(ck);
    float sB = wsum(cb);
    if (t == 0) { cc[0] = sC; cc[1] = sB + be2[0]; }
  }
  __syncthreads();
  float C1 = cc[0], C0 = cc[1];

  float S1[4], S2[4], Sc[4];
#pragma unroll
  for (int q = 0; q < 4; q++) { S1[q] = 0.f; S2[q] = 0.f; Sc[q] = 0.f; }
  const float* Ub = &Ut[(wv * 4) * 64];
  for (int k4 = 0; k4 < 16; k4++) {
    float4 v4 = *(const float4*)&V[lane * 68 + k4 * 4];
    float4 c4 = *(const float4*)&C[k4 * 4];
#pragma unroll
    for (int q = 0; q < 4; q++) {
      float4 u4 = *(const float4*)&Ub[q * 64 + k4 * 4];   // uniform addr -> broadcast
      float t0 = fmaxf(u4.x + v4.x, 0.f);
      float t1 = fmaxf(u4.y + v4.y, 0.f);
      float t2 = fmaxf(u4.z + v4.z, 0.f);
      float t3 = fmaxf(u4.w + v4.w, 0.f);
      S1[q] += (t0 + t1) + (t2 + t3);
      S2[q] = fmaf(t0, t0, fmaf(t1, t1, fmaf(t2, t2, fmaf(t3, t3, S2[q]))));
      Sc[q] = fmaf(t0, c4.x, fmaf(t1, c4.y, fmaf(t2, c4.z, fmaf(t3, c4.w, Sc[q]))));
    }
  }
  int j = cg * 64 + lane;
  const float inv64 = 1.0f / 64.0f;
#pragma unroll
  for (int q = 0; q < 4; q++) {
    int i = rg * 16 + wv * 4 + q;
    if (j > i) {
      int pbase = i * (2 * NN - i - 1) / 2 - i - 1;
      float mu = S1[q] * inv64;
      float var = fmaf(-mu, mu, S2[q] * inv64);
      float logit = (Sc[q] - mu * C1) * rsqrtf(var + 1e-5f) + C0;
      out[EL_OFF + pbase + j] = logit;
    }
  }
}

extern "C" void kernel_launch(void* const* d_in, const int* in_sizes, int n_in,
                              void* d_out, int out_size, void* d_ws, size_t ws_size,
                              hipStream_t stream) {
  const float* x    = (const float*)d_in[0];
  const int*   ei   = (const int*)d_in[1];
  const float* eps  = (const float*)d_in[2];
  // d_in[3] = eps_graph: z_graph computed but unused downstream -> skip
  const float* Wl1  = (const float*)d_in[4];
  const float* bl1  = (const float*)d_in[5];
  const float* Wr1  = (const float*)d_in[6];
  const float* br1  = (const float*)d_in[7];
  const float* att1 = (const float*)d_in[8];
  const float* bias1= (const float*)d_in[9];
  const float* Wl2  = (const float*)d_in[10];
  const float* bl2  = (const float*)d_in[11];
  const float* Wr2  = (const float*)d_in[12];
  const float* br2  = (const float*)d_in[13];
  const float* att2 = (const float*)d_in[14];
  const float* bias2= (const float*)d_in[15];
  const float* Wnm  = (const float*)d_in[16];
  const float* bnm  = (const float*)d_in[17];
  const float* Wnv  = (const float*)d_in[18];
  const float* bnv  = (const float*)d_in[19];
  const float* Wgm  = (const float*)d_in[20];
  const float* bgm  = (const float*)d_in[21];
  const float* Wgv  = (const float*)d_in[22];
  const float* bgv  = (const float*)d_in[23];
  const float* Wd1  = (const float*)d_in[24];
  const float* bd1  = (const float*)d_in[25];
  const float* ln1g = (const float*)d_in[26];
  const float* ln1b = (const float*)d_in[27];
  const float* Wd2  = (const float*)d_in[28];
  const float* bd2  = (const float*)d_in[29];
  const float* ln2g = (const float*)d_in[30];
  const float* ln2b = (const float*)d_in[31];
  const float* Wd3  = (const float*)d_in[32];
  const float* bd3  = (const float*)d_in[33];
  const float* We1  = (const float*)d_in[34];
  const float* be1  = (const float*)d_in[35];
  const float* lneg = (const float*)d_in[36];
  const float* lneb = (const float*)d_in[37];
  const float* We2  = (const float*)d_in[38];
  const float* be2  = (const float*)d_in[39];
  const float* Wf1  = (const float*)d_in[40];
  const float* bf1  = (const float*)d_in[41];
  const float* lnfg = (const float*)d_in[42];
  const float* lnfb = (const float*)d_in[43];
  const float* Wf2  = (const float*)d_in[44];
  const float* bf2  = (const float*)d_in[45];
  float* out = (float*)d_out;

  // workspace layout
  float* fb  = (float*)d_ws;
  float* xl1 = fb;
  float* xr1 = xl1 + NN * HD;
  float* xl2 = xr1 + NN * HD;
  float* xr2 = xl2 + NN * HD;
  float* uu  = xr2 + NN * HD;
  float* vv  = uu  + NN * HD;
  float* h2  = vv  + NN * HD;          // NN*64
  float* zz  = h2  + NN * HD;          // NN*32
  float* gh  = zz  + NN * LDIM;        // 64 floats (zeroed)
  int* cnt    = (int*)(gh + HD);       // NN ints (zeroed)
  unsigned short* slot = (unsigned short*)(cnt + NN);  // NN*CAP u16 (bounded by cnt)

  // zero gh + cnt (contiguous, 1600 dwords)
  hipMemsetAsync(gh, 0, (HD + NN) * sizeof(float), stream);

  gvae_xform1<<<NN / 4, 256, 0, stream>>>(x, Wl1, bl1, Wr1, br1, xl1, xr1,
                                          ei, cnt, slot);
  gvae_gatherx<<<NN / 4, 512, 0, stream>>>(cnt, slot, xl1, xr1, att1, bias1,
                                           Wl2, bl2, Wr2, br2, xl2, xr2);
  gvae_node<<<NN / 4, 512, 0, stream>>>(cnt, slot, xl2, xr2, att2, bias2, eps,
      Wnm, bnm, Wnv, bnv, We1, be1,
      uu, vv, h2, zz, gh, out);
  gvae_edge<<<NTILE + NN / 4, 256, 0, stream>>>(uu, vv, lneg, lneb, We2, be2,
      gh, Wgm, bgm, Wgv, bgv,
      h2, zz,
      Wd1, bd1, ln1g, ln1b, Wd2, bd2, ln2g, ln2b, Wd3, bd3,
      Wf1, bf1, lnfg, lnfb, Wf2, bf2,
      out);
}

// Round 11
// 212.649 us; speedup vs baseline: 1.0678x; 1.0009x over previous
//
#include <hip/hip_runtime.h>

#define NN 1536
#define NE 49152
#define FIN 27
#define HD 64
#define LDIM 32
#define PP 1178880        // NN*(NN-1)/2
#define CAP 128           // padded-CSR row capacity (in-deg ~Poisson(32); passed at 128)
#define NTILE 1200        // 16x64 upper-tri tiles: sum_{cg=0..23} 4*(cg+1)
#define NDEC (NN / 4)     // 384 decoder blocks, dispatched FIRST (latency-bound, hide under tiles)

#define EL_OFF  (NN*FIN)            // 41472
#define MU_OFF  (EL_OFF + PP)       // 1220352
#define LV_OFF  (MU_OFF + NN*LDIM)  // 1269504
#define GMU_OFF (LV_OFF + NN*LDIM)  // 1318656
#define GLV_OFF (GMU_OFF + LDIM)    // 1318688

__device__ __forceinline__ float wsum(float v) {
#pragma unroll
  for (int m = 1; m < 64; m <<= 1) v += __shfl_xor(v, m, 64);
  return v;
}
__device__ __forceinline__ void wsum2(float& a, float& b) {
#pragma unroll
  for (int m = 1; m < 64; m <<= 1) {
    a += __shfl_xor(a, m, 64);
    b += __shfl_xor(b, m, 64);
  }
}
__device__ __forceinline__ void wsum4(float& a, float& b, float& c, float& d) {
#pragma unroll
  for (int m = 1; m < 64; m <<= 1) {
    a += __shfl_xor(a, m, 64);
    b += __shfl_xor(b, m, 64);
    c += __shfl_xor(c, m, 64);
    d += __shfl_xor(d, m, 64);
  }
}
__device__ __forceinline__ float lnorm64(float x, float g, float b) {
  float s1 = x, s2 = x * x;
  wsum2(s1, s2);
  float mu = s1 * (1.0f / 64.0f);
  float var = fmaf(-mu, mu, s2 * (1.0f / 64.0f));
  return (x - mu) * rsqrtf(var + 1e-5f) * g + b;
}
__device__ __forceinline__ void cp4(float* dst, const float* __restrict__ src,
                                    int n4, int t) {
  const float4* s4 = (const float4*)src;
  float4* d4 = (float4*)dst;
  for (int e = t; e < n4; e += 256) d4[e] = s4[e];
}

// ---------------- GATv2 gather, HALF-wave-split (r8-exact): wave h handles ----------------
// j in [32h,32h+32) of each 64-edge batch; partials combined via LDS. Self-loop by h==1.
__device__ __forceinline__ void gat_gather_half(
    const int* __restrict__ cnt, const unsigned short* __restrict__ slot,
    const float* __restrict__ xl, float xri, float ak, int i, int k, int h,
    float& accO, float& denO) {
  int n = min(cnt[i], CAP);
  const unsigned short* srow = slot + i * CAP;
  float acc = 0.f, den = 0.f;
  for (int e0 = 0; e0 < n; e0 += 64) {
    int sidx = (e0 + k < n) ? (int)srow[e0 + k] : 0;   // 64 srcs, 128B coalesced
    int nn = min(64, n - e0);
    int jbeg = h * 32;
    int jend = min(nn, jbeg + 32);
    int j = jbeg;
    for (; j + 3 < jend; j += 4) {
      int s0 = __shfl(sidx, j, 64),     s1 = __shfl(sidx, j + 1, 64);
      int s2 = __shfl(sidx, j + 2, 64), s3 = __shfl(sidx, j + 3, 64);
      float x0 = xl[s0 * HD + k], x1 = xl[s1 * HD + k];
      float x2 = xl[s2 * HD + k], x3 = xl[s3 * HD + k];
      float e0v = x0 + xri, e1v = x1 + xri, e2v = x2 + xri, e3v = x3 + xri;
      e0v = fmaxf(e0v, 0.2f * e0v);
      e1v = fmaxf(e1v, 0.2f * e1v);
      e2v = fmaxf(e2v, 0.2f * e2v);
      e3v = fmaxf(e3v, 0.2f * e3v);
      float p0 = e0v * ak, p1 = e1v * ak, p2 = e2v * ak, p3 = e3v * ak;
      wsum4(p0, p1, p2, p3);
      float w0 = expf(p0), w1 = expf(p1), w2 = expf(p2), w3 = expf(p3);
      acc = fmaf(w0, x0, acc); den += w0;
      acc = fmaf(w1, x1, acc); den += w1;
      acc = fmaf(w2, x2, acc); den += w2;
      acc = fmaf(w3, x3, acc); den += w3;
    }
    for (; j < jend; ++j) {
      int s0 = __shfl(sidx, j, 64);
      float x0 = xl[s0 * HD + k];
      float e0v = x0 + xri;
      e0v = fmaxf(e0v, 0.2f * e0v);
      float w0 = expf(wsum(e0v * ak));
      acc = fmaf(w0, x0, acc); den += w0;
    }
  }
  if (h == 1) {   // self loop, appended last
    float xs = xl[i * HD + k];
    float es = xs + xri;
    es = fmaxf(es, 0.2f * es);
    float ws = expf(wsum(es * ak));
    acc = fmaf(ws, xs, acc); den += ws;
  }
  accO = acc; denO = den;
}

// ---------------- layer-1 transform + inline padded-CSR build (slot=u16) ----------------
__global__ __launch_bounds__(256) void gvae_xform1(
    const float* __restrict__ in,
    const float* __restrict__ Wl, const float* __restrict__ bl,
    const float* __restrict__ Wr, const float* __restrict__ br,
    float* __restrict__ xl, float* __restrict__ xr,
    const int* __restrict__ ei, int* __restrict__ cnt,
    unsigned short* __restrict__ slot) {
  __shared__ __align__(16) float sWl[FIN * HD];
  __shared__ __align__(16) float sWr[FIN * HD];
  int t = threadIdx.x;
  int gid = blockIdx.x * 256 + t;
  if (gid < NE) {
    int d = ei[NE + gid];
    int c = atomicAdd(&cnt[d], 1);
    if (c < CAP) slot[d * CAP + c] = (unsigned short)ei[gid];
  }
  cp4(sWl, Wl, FIN * 16, t);
  cp4(sWr, Wr, FIN * 16, t);
  int i = blockIdx.x * 4 + (t >> 6);
  int k = t & 63;
  float xv = (k < FIN) ? in[i * FIN + k] : 0.f;
  float l0 = bl[k], l1 = 0.f, r0 = br[k], r1 = 0.f;
  __syncthreads();
#pragma unroll
  for (int a = 0; a < FIN; a += 2) {
    float xa = __shfl(xv, a, 64);
    l0 = fmaf(xa, sWl[a * HD + k], l0);
    r0 = fmaf(xa, sWr[a * HD + k], r0);
    if (a + 1 < FIN) {
      float xb = __shfl(xv, a + 1, 64);
      l1 = fmaf(xb, sWl[(a + 1) * HD + k], l1);
      r1 = fmaf(xb, sWr[(a + 1) * HD + k], r1);
    }
  }
  xl[i * HD + k] = l0 + l1;
  xr[i * HD + k] = r0 + r1;
}

// ---------------- fused GAT-1 gather (2 waves/node) + layer-2 transform (r8-exact) ----------------
__global__ __launch_bounds__(512, 4) void gvae_gatherx(
    const int* __restrict__ cnt, const unsigned short* __restrict__ slot,
    const float* __restrict__ xl, const float* __restrict__ xr,
    const float* __restrict__ att, const float* __restrict__ hbias,
    const float* __restrict__ Wl, const float* __restrict__ bl,
    const float* __restrict__ Wr, const float* __restrict__ br,
    float* __restrict__ xlo, float* __restrict__ xro) {
  __shared__ float sA[4][2][64];
  __shared__ float sD[4][2][64];
  int t = threadIdx.x;
  int wv = t >> 6, k = t & 63;
  int p = wv >> 1, h = wv & 1;
  int i = blockIdx.x * 4 + p;
  float xri = xr[i * HD + k];
  float ak = att[k];
  float pa, pd;
  gat_gather_half(cnt, slot, xl, xri, ak, i, k, h, pa, pd);
  sA[p][h][k] = pa;
  sD[p][h][k] = pd;
  __syncthreads();
  float hv = fmaxf((sA[p][0][k] + sA[p][1][k]) / (sD[p][0][k] + sD[p][1][k])
                   + hbias[k], 0.f);
  const float* W = h ? Wr : Wl;
  float c0 = h ? br[k] : bl[k];
  float c1 = 0.f, c2 = 0.f, c3 = 0.f;
#pragma unroll
  for (int a = 0; a < HD; a += 4) {
    c0 = fmaf(__shfl(hv, a, 64),     W[a * HD + k],       c0);
    c1 = fmaf(__shfl(hv, a + 1, 64), W[(a + 1) * HD + k], c1);
    c2 = fmaf(__shfl(hv, a + 2, 64), W[(a + 2) * HD + k], c2);
    c3 = fmaf(__shfl(hv, a + 3, 64), W[(a + 3) * HD + k], c3);
  }
  float r = (c0 + c1) + (c2 + c3);
  if (h == 0) xlo[i * HD + k] = r;
  else        xro[i * HD + k] = r;
}

// ---------------- GAT-2 gather (2 waves/node) + encoder head (r8-exact) ----------------
__global__ __launch_bounds__(512, 4) void gvae_node(
    const int* __restrict__ cnt, const unsigned short* __restrict__ slot,
    const float* __restrict__ xl, const float* __restrict__ xr,
    const float* __restrict__ att, const float* __restrict__ bias2,
    const float* __restrict__ eps,
    const float* __restrict__ Wnm, const float* __restrict__ bnm,
    const float* __restrict__ Wnv, const float* __restrict__ bnv,
    const float* __restrict__ We1, const float* __restrict__ be1,
    float* __restrict__ uo, float* __restrict__ vo,
    float* __restrict__ h2o, float* __restrict__ zzo,
    float* __restrict__ gh, float* __restrict__ out) {
  __shared__ float sA[4][2][64];
  __shared__ float sD[4][2][64];
  __shared__ float sZ[4][32];
  __shared__ float ghred[256];
  int t = threadIdx.x;
  int wv = t >> 6, k = t & 63;
  int p = wv >> 1, h = wv & 1;
  int i = blockIdx.x * 4 + p;
  int kk = k & 31;

  float xri = xr[i * HD + k];
  float ak = att[k];
  float pa, pd;
  gat_gather_half(cnt, slot, xl, xri, ak, i, k, h, pa, pd);
  sA[p][h][k] = pa;
  sD[p][h][k] = pd;
  __syncthreads();
  float h2k = fmaxf((sA[p][0][k] + sA[p][1][k]) / (sD[p][0][k] + sD[p][1][k])
                    + bias2[k], 0.f);
  if (h == 0) {
    h2o[i * HD + k] = h2k;
    ghred[p * 64 + k] = h2k;
  }
  __syncthreads();
  if (t < 64) {               // one atomic per block per k (4 nodes summed)
    float s = (ghred[t] + ghred[t + 64]) + (ghred[t + 128] + ghred[t + 192]);
    atomicAdd(&gh[t], s * (1.0f / NN));
  }

  if (h == 0) {
    // node_mu (lanes 0..31) / node_logvar (lanes 32..63)
    const float* W = (k < 32) ? Wnm : Wnv;
    float c0 = (k < 32) ? bnm[kk] : bnv[kk];
    float c1 = 0.f, c2 = 0.f, c3 = 0.f;
#pragma unroll
    for (int a = 0; a < HD; a += 4) {
      c0 = fmaf(__shfl(h2k, a, 64),     W[a * LDIM + kk],       c0);
      c1 = fmaf(__shfl(h2k, a + 1, 64), W[(a + 1) * LDIM + kk], c1);
      c2 = fmaf(__shfl(h2k, a + 2, 64), W[(a + 2) * LDIM + kk], c2);
      c3 = fmaf(__shfl(h2k, a + 3, 64), W[(a + 3) * LDIM + kk], c3);
    }
    float acc = (c0 + c1) + (c2 + c3);
    if (k < 32) out[MU_OFF + i * LDIM + kk] = acc;
    else        out[LV_OFF + i * LDIM + kk] = acc;

    // z = mu + eps * exp(0.5*logvar)  (valid lanes 0..31)
    float lv = __shfl(acc, k + 32, 64);
    float zk = acc + eps[i * LDIM + kk] * expf(0.5f * lv);
    if (k < 32) {
      zzo[i * LDIM + kk] = zk;
      sZ[p][kk] = zk;
    }
  }
  __syncthreads();
  if (h == 1) {
    // u = z@We1[:32] + be1 ; v = z@We1[32:]
    float zk = sZ[p][kk];
    float u0 = be1[k], u1 = 0.f, v0 = 0.f, v1 = 0.f;
#pragma unroll
    for (int a = 0; a < LDIM; a += 2) {
      float za = __shfl(zk, a, 64);
      float zb = __shfl(zk, a + 1, 64);
      u0 = fmaf(za, We1[a * HD + k], u0);
      u1 = fmaf(zb, We1[(a + 1) * HD + k], u1);
      v0 = fmaf(za, We1[(a + LDIM) * HD + k], v0);
      v1 = fmaf(zb, We1[(a + 1 + LDIM) * HD + k], v1);
    }
    uo[i * HD + k] = u0 + u1;
    vo[i * HD + k] = v0 + v1;
  }
}

// ---------------- edge kernel: DECODER blocks first (b<NDEC, latency-bound, hide ----------------
// under tiles), then 1200 tile blocks (throughput-bound). Math bit-identical to r10;
// only the blockIdx role mapping changed (decoder was the serial tail at b>=NTILE).
__global__ __launch_bounds__(256) void gvae_edge(
    const float* __restrict__ u, const float* __restrict__ v,
    const float* __restrict__ lng, const float* __restrict__ lnb,
    const float* __restrict__ w2, const float* __restrict__ be2,
    const float* __restrict__ gh,
    const float* __restrict__ Wgm, const float* __restrict__ bgm,
    const float* __restrict__ Wgv, const float* __restrict__ bgv,
    const float* __restrict__ h2, const float* __restrict__ zz,
    const float* __restrict__ Wd1, const float* __restrict__ bd1,
    const float* __restrict__ g1, const float* __restrict__ b1,
    const float* __restrict__ Wd2, const float* __restrict__ bd2,
    const float* __restrict__ g2, const float* __restrict__ b2,
    const float* __restrict__ Wd3, const float* __restrict__ bd3,
    const float* __restrict__ Wf1, const float* __restrict__ bf1,
    const float* __restrict__ gf, const float* __restrict__ bfv,
    const float* __restrict__ Wf2, const float* __restrict__ bf2,
    float* __restrict__ out) {
  __shared__ float V[64 * 68];
  __shared__ __align__(16) float Ut[16 * 64];
  __shared__ float C[64];
  __shared__ float cc[2];
  int t = threadIdx.x;
  int b = blockIdx.x;
  int wv = t >> 6, lane = t & 63;

  if (b < NDEC) {
    // ============ decoder block: 4 nodes, 1 wave each (dispatched FIRST) ============
    int i = b * 4 + wv;
    int k = lane;
    int kc = (k < FIN) ? k : (FIN - 1);
    float h2k = h2[i * HD + k];
    float zk = zz[i * LDIM + (k & 31)];

    float c0 = bd1[k], c1 = 0.f, c2 = 0.f, c3 = 0.f;
#pragma unroll
    for (int a = 0; a < LDIM; a += 4) {
      c0 = fmaf(__shfl(zk, a, 64),     Wd1[a * HD + k],       c0);
      c1 = fmaf(__shfl(zk, a + 1, 64), Wd1[(a + 1) * HD + k], c1);
      c2 = fmaf(__shfl(zk, a + 2, 64), Wd1[(a + 2) * HD + k], c2);
      c3 = fmaf(__shfl(zk, a + 3, 64), Wd1[(a + 3) * HD + k], c3);
    }
    float nf1 = lnorm64(fmaxf((c0 + c1) + (c2 + c3), 0.f), g1[k], b1[k]);

    c0 = bd2[k]; c1 = 0.f; c2 = 0.f; c3 = 0.f;
#pragma unroll
    for (int a = 0; a < HD; a += 4) {
      c0 = fmaf(__shfl(nf1, a, 64),     Wd2[a * HD + k],       c0);
      c1 = fmaf(__shfl(nf1, a + 1, 64), Wd2[(a + 1) * HD + k], c1);
      c2 = fmaf(__shfl(nf1, a + 2, 64), Wd2[(a + 2) * HD + k], c2);
      c3 = fmaf(__shfl(nf1, a + 3, 64), Wd2[(a + 3) * HD + k], c3);
    }
    float nf2 = lnorm64(fmaxf((c0 + c1) + (c2 + c3), 0.f), g2[k], b2[k]);

    c0 = 0.f; c1 = 0.f; c2 = 0.f; c3 = 0.f;
#pragma unroll
    for (int a = 0; a < HD; a += 4) {
      c0 = fmaf(__shfl(nf2, a, 64),     Wd3[a * FIN + kc],       c0);
      c1 = fmaf(__shfl(nf2, a + 1, 64), Wd3[(a + 1) * FIN + kc], c1);
      c2 = fmaf(__shfl(nf2, a + 2, 64), Wd3[(a + 2) * FIN + kc], c2);
      c3 = fmaf(__shfl(nf2, a + 3, 64), Wd3[(a + 3) * FIN + kc], c3);
    }
    float nf3 = (k < FIN) ? ((c0 + c1) + (c2 + c3) + bd3[kc]) : 0.f;

    c0 = bf1[k]; c1 = 0.f; c2 = 0.f; c3 = 0.f;
#pragma unroll
    for (int j = 0; j < FIN; j++) {
      float nj = __shfl(nf3, j, 64);
      c0 = fmaf(nj, Wf1[j * HD + k], c0);
    }
#pragma unroll
    for (int a = 0; a < HD; a += 4) {
      c0 = fmaf(__shfl(h2k, a, 64),     Wf1[(FIN + a) * HD + k],     c0);
      c1 = fmaf(__shfl(h2k, a + 1, 64), Wf1[(FIN + a + 1) * HD + k], c1);
      c2 = fmaf(__shfl(h2k, a + 2, 64), Wf1[(FIN + a + 2) * HD + k], c2);
      c3 = fmaf(__shfl(h2k, a + 3, 64), Wf1[(FIN + a + 3) * HD + k], c3);
    }
    float rr = lnorm64(fmaxf((c0 + c1) + (c2 + c3), 0.f), gf[k], bfv[k]);

    c0 = 0.f; c1 = 0.f; c2 = 0.f; c3 = 0.f;
#pragma unroll
    for (int a = 0; a < HD; a += 4) {
      c0 = fmaf(__shfl(rr, a, 64),     Wf2[a * FIN + kc],       c0);
      c1 = fmaf(__shfl(rr, a + 1, 64), Wf2[(a + 1) * FIN + kc], c1);
      c2 = fmaf(__shfl(rr, a + 2, 64), Wf2[(a + 2) * FIN + kc], c2);
      c3 = fmaf(__shfl(rr, a + 3, 64), Wf2[(a + 3) * FIN + kc], c3);
    }
    if (k < FIN) out[i * FIN + k] = (c0 + c1) + (c2 + c3) + bf2[kc];
    return;
  }

  // ============ tile block: 16 rows x 64 cols ============
  int tb = b - NDEC;
  if (tb == 0 && wv == 3) {   // fused graph head
    int kk = lane & 31;
    float ghk = gh[lane];
    const float* W = (lane < 32) ? Wgm : Wgv;
    float c0 = (lane < 32) ? bgm[kk] : bgv[kk];
    float c1 = 0.f, c2 = 0.f, c3 = 0.f;
#pragma unroll
    for (int a = 0; a < HD; a += 4) {
      c0 = fmaf(__shfl(ghk, a, 64),     W[a * LDIM + kk],       c0);
      c1 = fmaf(__shfl(ghk, a + 1, 64), W[(a + 1) * LDIM + kk], c1);
      c2 = fmaf(__shfl(ghk, a + 2, 64), W[(a + 2) * LDIM + kk], c2);
      c3 = fmaf(__shfl(ghk, a + 3, 64), W[(a + 3) * LDIM + kk], c3);
    }
    float acc = (c0 + c1) + (c2 + c3);
    if (lane < 32) out[GMU_OFF + kk] = acc;
    else           out[GLV_OFF + kk] = acc;
  }

  int rem = tb, cg = 0;
  while (rem >= 4 * (cg + 1)) { rem -= 4 * (cg + 1); cg++; }
  int rg = rem;

  // stage U (16 rows x 64 dims) into LDS for wave-uniform broadcast reads
  {
    int r = t >> 4, d4 = t & 15;
    const float4* u4p = (const float4*)(u + (rg * 16) * HD);
    *(float4*)&Ut[r * 64 + d4 * 4] = u4p[r * 16 + d4];
  }

  // stage V (64 nodes x 64 dims, stride 68) via float4
  const float4* v4p = (const float4*)(v + cg * 64 * HD);
#pragma unroll
  for (int it = 0; it < 4; ++it) {
    int r = t + it * 256;
    int row = r >> 4, q = r & 15;
    float4 vv = v4p[r];
    *(float4*)&V[row * 68 + q * 4] = vv;
  }
  if (t < 64) {
    float ck = lng[t] * w2[t];
    C[t] = ck;
    float cb = lnb[t] * w2[t];
    float sC = wsum(ck);
    float sB = wsum(cb);
    if (t == 0) { cc[0] = sC; cc[1] = sB + be2[0]; }
  }
  __syncthreads();
  float C1 = cc[0], C0 = cc[1];

  float S1[4], S2[4], Sc[4];
#pragma unroll
  for (int q = 0; q < 4; q++) { S1[q] = 0.f; S2[q] = 0.f; Sc[q] = 0.f; }
  const float* Ub = &Ut[(wv * 4) * 64];
  for (int k4 = 0; k4 < 16; k4++) {
    float4 v4 = *(const float4*)&V[lane * 68 + k4 * 4];
    float4 c4 = *(const float4*)&C[k4 * 4];
#pragma unroll
    for (int q = 0; q < 4; q++) {
      float4 u4 = *(const float4*)&Ub[q * 64 + k4 * 4];   // uniform addr -> broadcast
      float t0 = fmaxf(u4.x + v4.x, 0.f);
      float t1 = fmaxf(u4.y + v4.y, 0.f);
      float t2 = fmaxf(u4.z + v4.z, 0.f);
      float t3 = fmaxf(u4.w + v4.w, 0.f);
      S1[q] += (t0 + t1) + (t2 + t3);
      S2[q] = fmaf(t0, t0, fmaf(t1, t1, fmaf(t2, t2, fmaf(t3, t3, S2[q]))));
      Sc[q] = fmaf(t0, c4.x, fmaf(t1, c4.y, fmaf(t2, c4.z, fmaf(t3, c4.w, Sc[q]))));
    }
  }
  int j = cg * 64 + lane;
  const float inv64 = 1.0f / 64.0f;
#pragma unroll
  for (int q = 0; q < 4; q++) {
    int i = rg * 16 + wv * 4 + q;
    if (j > i) {
      int pbase = i * (2 * NN - i - 1) / 2 - i - 1;
      float mu = S1[q] * inv64;
      float var = fmaf(-mu, mu, S2[q] * inv64);
      float logit = (Sc[q] - mu * C1) * rsqrtf(var + 1e-5f) + C0;
      out[EL_OFF + pbase + j] = logit;
    }
  }
}

extern "C" void kernel_launch(void* const* d_in, const int* in_sizes, int n_in,
                              void* d_out, int out_size, void* d_ws, size_t ws_size,
                              hipStream_t stream) {
  const float* x    = (const float*)d_in[0];
  const int*   ei   = (const int*)d_in[1];
  const float* eps  = (const float*)d_in[2];
  // d_in[3] = eps_graph: z_graph computed but unused downstream -> skip
  const float* Wl1  = (const float*)d_in[4];
  const float* bl1  = (const float*)d_in[5];
  const float* Wr1  = (const float*)d_in[6];
  const float* br1  = (const float*)d_in[7];
  const float* att1 = (const float*)d_in[8];
  const float* bias1= (const float*)d_in[9];
  const float* Wl2  = (const float*)d_in[10];
  const float* bl2  = (const float*)d_in[11];
  const float* Wr2  = (const float*)d_in[12];
  const float* br2  = (const float*)d_in[13];
  const float* att2 = (const float*)d_in[14];
  const float* bias2= (const float*)d_in[15];
  const float* Wnm  = (const float*)d_in[16];
  const float* bnm  = (const float*)d_in[17];
  const float* Wnv  = (const float*)d_in[18];
  const float* bnv  = (const float*)d_in[19];
  const float* Wgm  = (const float*)d_in[20];
  const float* bgm  = (const float*)d_in[21];
  const float* Wgv  = (const float*)d_in[22];
  const float* bgv  = (const float*)d_in[23];
  const float* Wd1  = (const float*)d_in[24];
  const float* bd1  = (const float*)d_in[25];
  const float* ln1g = (const float*)d_in[26];
  const float* ln1b = (const float*)d_in[27];
  const float* Wd2  = (const float*)d_in[28];
  const float* bd2  = (const float*)d_in[29];
  const float* ln2g = (const float*)d_in[30];
  const float* ln2b = (const float*)d_in[31];
  const float* Wd3  = (const float*)d_in[32];
  const float* bd3  = (const float*)d_in[33];
  const float* We1  = (const float*)d_in[34];
  const float* be1  = (const float*)d_in[35];
  const float* lneg = (const float*)d_in[36];
  const float* lneb = (const float*)d_in[37];
  const float* We2  = (const float*)d_in[38];
  const float* be2  = (const float*)d_in[39];
  const float* Wf1  = (const float*)d_in[40];
  const float* bf1  = (const float*)d_in[41];
  const float* lnfg = (const float*)d_in[42];
  const float* lnfb = (const float*)d_in[43];
  const float* Wf2  = (const float*)d_in[44];
  const float* bf2  = (const float*)d_in[45];
  float* out = (float*)d_out;

  // workspace layout
  float* fb  = (float*)d_ws;
  float* xl1 = fb;
  float* xr1 = xl1 + NN * HD;
  float* xl2 = xr1 + NN * HD;
  float* xr2 = xl2 + NN * HD;
  float* uu  = xr2 + NN * HD;
  float* vv  = uu  + NN * HD;
  float* h2  = vv  + NN * HD;          // NN*64
  float* zz  = h2  + NN * HD;          // NN*32
  float* gh  = zz  + NN * LDIM;        // 64 floats (zeroed)
  int* cnt    = (int*)(gh + HD);       // NN ints (zeroed)
  unsigned short* slot = (unsigned short*)(cnt + NN);  // NN*CAP u16 (bounded by cnt)

  // zero gh + cnt (contiguous, 1600 dwords)
  hipMemsetAsync(gh, 0, (HD + NN) * sizeof(float), stream);

  gvae_xform1<<<NN / 4, 256, 0, stream>>>(x, Wl1, bl1, Wr1, br1, xl1, xr1,
                                          ei, cnt, slot);
  gvae_gatherx<<<NN / 4, 512, 0, stream>>>(cnt, slot, xl1, xr1, att1, bias1,
                                           Wl2, bl2, Wr2, br2, xl2, xr2);
  gvae_node<<<NN / 4, 512, 0, stream>>>(cnt, slot, xl2, xr2, att2, bias2, eps,
      Wnm, bnm, Wnv, bnv, We1, be1,
      uu, vv, h2, zz, gh, out);
  gvae_edge<<<NTILE + NDEC, 256, 0, stream>>>(uu, vv, lneg, lneb, We2, be2,
      gh, Wgm, bgm, Wgv, bgv,
      h2, zz,
      Wd1, bd1, ln1g, ln1b, Wd2, bd2, ln2g, ln2b, Wd3, bd3,
      Wf1, bf1, lnfg, lnfb, Wf2, bf2,
      out);
}